// Round 1
// baseline (761.441 us; speedup 1.0000x reference)
//
#include <hip/hip_runtime.h>
#include <hip/hip_bf16.h>
#include <stdint.h>

#define IN_F 4096
#define OUT_F 4096
#define NE 64
#define TOPK 16
#define RD 16
#define BOT 512
#define NTOK 16384

typedef __attribute__((ext_vector_type(8))) short short8;
typedef __attribute__((ext_vector_type(4))) float floatx4;

__device__ __forceinline__ unsigned short f2bf_ru(float f) {
  unsigned int u = __float_as_uint(f);
  return (unsigned short)((u + 0x8000u) >> 16);
}
__device__ __forceinline__ unsigned short f2bf_rne(float f) {
  unsigned int u = __float_as_uint(f);
  return (unsigned short)((u + 0x7FFFu + ((u >> 16) & 1u)) >> 16);
}

// async global->LDS, 16B per lane. LDS dest must be wave-uniform base (+lane*16 by HW).
__device__ __forceinline__ void gl2lds16(const void* g, void* l) {
  __builtin_amdgcn_global_load_lds(
      (const __attribute__((address_space(1))) unsigned int*)g,
      (__attribute__((address_space(3))) unsigned int*)l, 16, 0, 0);
}

// ---------------- prep: convert A_w, B_w to bf16 ----------------
__global__ __launch_bounds__(256) void prep_kernel(
    const float* __restrict__ A_w, const float* __restrict__ B_w,
    unsigned short* __restrict__ Abf, unsigned short* __restrict__ Bbf) {
  int i = blockIdx.x * 256 + threadIdx.x;
  if (i < BOT * IN_F) {
    Abf[i] = f2bf_rne(A_w[i]);
    Bbf[i] = f2bf_rne(B_w[i]);
  }
}

// ---------------- router: fp32 LDS staging, fp64 accum (identical order ->
// bit-identical scores vs verified fp64 path), top-16, softmax -> dense gate.
// Also emits x_bf (bf16 x) for the MFMA stageA fast path.
// block = 256 threads, 32 tokens per block, grid = 512
__global__ __launch_bounds__(256) void router_kernel(
    const float* __restrict__ x, const float* __restrict__ Wq,
    const float* __restrict__ keys, float* __restrict__ gate,
    unsigned short* __restrict__ xbf, int write_xbf) {
  __shared__ float x_lds[32][132];   // fp32 staging (was fp64): half the LDS bytes
  __shared__ float wq_lds[16][132];
  __shared__ double q_lds[32][16];
  __shared__ double sc[32][64];
  const int tid = threadIdx.x;
  const size_t t0 = (size_t)blockIdx.x * 32;
  const int r = tid & 15, tg = tid >> 4;
  double acc0 = 0.0, acc1 = 0.0;

  for (int kc = 0; kc < IN_F; kc += 128) {
    __syncthreads();
    // stage x chunk (32 rows x 128 floats) as fp32; fused bf16-x emission
    for (int i = 0; i < 4; i++) {
      int f = i * 256 + tid;
      int row = f >> 5, c = (f & 31) * 4;
      float4 v = *(const float4*)(x + (t0 + row) * IN_F + kc + c);
      *(float4*)(&x_lds[row][c]) = v;
      if (write_xbf) {
        ushort4 h;
        h.x = f2bf_ru(v.x); h.y = f2bf_ru(v.y);
        h.z = f2bf_ru(v.z); h.w = f2bf_ru(v.w);
        *(ushort4*)(xbf + (t0 + row) * IN_F + kc + c) = h;
      }
    }
    // stage Wq chunk (16 rows x 128 floats) as fp32
    for (int i = 0; i < 2; i++) {
      int f = i * 256 + tid;
      int row = f >> 5, c = (f & 31) * 4;
      *(float4*)(&wq_lds[row][c]) = *(const float4*)(Wq + (size_t)row * IN_F + kc + c);
    }
    __syncthreads();
    const float* xr0 = x_lds[tg * 2];
    const float* xr1 = x_lds[tg * 2 + 1];
    const float* wr = wq_lds[r];
#pragma unroll 8
    for (int k = 0; k < 128; k += 2) {
      float2 w = *(const float2*)(wr + k);
      float2 a = *(const float2*)(xr0 + k);
      float2 b = *(const float2*)(xr1 + k);
      double wx = (double)w.x, wy = (double)w.y;
      // same accumulation order as verified kernel -> bit-identical q
      acc0 += (double)a.x * wx; acc0 += (double)a.y * wy;
      acc1 += (double)b.x * wx; acc1 += (double)b.y * wy;
    }
  }
  q_lds[tg * 2][r] = acc0;
  q_lds[tg * 2 + 1][r] = acc1;
  __syncthreads();

  // scores[t][e] = sum_r q[t][r] * keys[e][r]   (fp64)
  {
    int t = tid >> 3, e0 = (tid & 7) * 8;
    for (int e = e0; e < e0 + 8; e++) {
      double s = 0.0;
      for (int rr = 0; rr < 16; rr++) s += q_lds[t][rr] * (double)keys[e * RD + rr];
      sc[t][e] = s;
    }
  }
  __syncthreads();

  // top-16 (ties -> lowest index, matching lax.top_k), softmax, scatter
  if (tid < 32) {
    int t = tid;
    double vals[16]; int idx[16];
    unsigned long long used = 0ull;
    for (int s = 0; s < 16; s++) {
      double best = -1e300; int bi = 0;
      for (int e = 0; e < 64; e++) {
        double v = sc[t][e];
        if (!((used >> e) & 1ull) && v > best) { best = v; bi = e; }
      }
      used |= (1ull << bi);
      vals[s] = best; idx[s] = bi;
    }
    double mx = vals[0], sum = 0.0, w[16];
    for (int i = 0; i < 16; i++) { w[i] = exp(vals[i] - mx); sum += w[i]; }
    double inv = 1.0 / sum;
    float* grow = gate + (t0 + t) * NE;
    for (int e = 0; e < 64; e++) grow[e] = 0.0f;
    for (int i = 0; i < 16; i++) grow[idx[i]] = (float)(w[i] * inv);
  }
}

// ---------------- stage A (fast): z = (x_bf @ A^T) * gate, bf16 out ----------------
// m97 structure: 128x128 tile, BK=32, global_load_lds dwordx4 staging, grid = 512
__global__ __launch_bounds__(256) void stageA_fast(
    const unsigned short* __restrict__ xbf, const unsigned short* __restrict__ Abf,
    const float* __restrict__ gate, unsigned short* __restrict__ z) {
  __shared__ unsigned short As[128 * 32];
  __shared__ unsigned short Bs[128 * 32];
  __shared__ float gl[128 * 16];
  const int tid = threadIdx.x;
  const int bid = blockIdx.x;
  // XCD swizzle: each XCD (bid&7) owns a contiguous band of 16 m-tiles x 4 n-tiles
  const int xc = bid & 7, ii = bid >> 3;
  const int mt = xc * 16 + (ii >> 2);
  const int nt = ii & 3;
  const size_t m0 = (size_t)mt * 128;
  const int n0 = nt * 128;
  const int wid = tid >> 6, lane = tid & 63;

  // gate tile: 128 tokens x 16 experts covered by this n-range
  for (int i = 0; i < 8; i++) {
    int f = i * 256 + tid;
    gl[f] = gate[(m0 + (f >> 4)) * NE + (n0 >> 3) + (f & 15)];
  }
  const int wm = (wid & 1) * 64, wn = (wid >> 1) * 64;
  const int lr = lane & 15, lq = lane >> 4;
  floatx4 acc[4][4];
  for (int i = 0; i < 4; i++)
    for (int j = 0; j < 4; j++) acc[i][j] = 0.0f;

  // per-lane staging geometry: chunk q = c*256 + wid*64 + lane; row = q>>2, col = (q&3)*8
  const int q0 = wid * 64 + lane;
  const int r0 = q0 >> 2, c0 = (q0 & 3) * 8;
  const int q1 = 256 + q0;
  const int r1 = q1 >> 2, c1 = (q1 & 3) * 8;
  const unsigned short* gA0 = xbf + (m0 + r0) * IN_F + c0;
  const unsigned short* gA1 = xbf + (m0 + r1) * IN_F + c1;
  const unsigned short* gB0 = Abf + (size_t)(n0 + r0) * IN_F + c0;
  const unsigned short* gB1 = Abf + (size_t)(n0 + r1) * IN_F + c1;
  unsigned short* lA0 = As + (wid * 64) * 8;
  unsigned short* lA1 = As + (256 + wid * 64) * 8;
  unsigned short* lB0 = Bs + (wid * 64) * 8;
  unsigned short* lB1 = Bs + (256 + wid * 64) * 8;

  for (int k0 = 0; k0 < IN_F; k0 += 32) {
    gl2lds16(gA0 + k0, lA0);
    gl2lds16(gA1 + k0, lA1);
    gl2lds16(gB0 + k0, lB0);
    gl2lds16(gB1 + k0, lB1);
    __syncthreads();  // drains vmcnt: tile resident
    short8 a[4], b[4];
    for (int i = 0; i < 4; i++) a[i] = *(const short8*)(As + (wm + i * 16 + lr) * 32 + lq * 8);
    for (int j = 0; j < 4; j++) b[j] = *(const short8*)(Bs + (wn + j * 16 + lr) * 32 + lq * 8);
    for (int i = 0; i < 4; i++)
      for (int j = 0; j < 4; j++)
        acc[i][j] = __builtin_amdgcn_mfma_f32_16x16x32_bf16(a[i], b[j], acc[i][j], 0, 0, 0);
    __syncthreads();  // readers done before next overwrite
  }
  // epilogue: gate + bf16 store (identical numerics to verified kernel)
  for (int i = 0; i < 4; i++) {
    for (int j = 0; j < 4; j++) {
      int cl = wn + j * 16 + lr;
      int el = cl >> 3;
      for (int g = 0; g < 4; g++) {
        int rl = wm + i * 16 + lq * 4 + g;
        float v = acc[i][j][g] * gl[rl * 16 + el];
        z[(m0 + rl) * BOT + n0 + cl] = f2bf_ru(v);
      }
    }
  }
}

// ---------------- stage A (fallback, verified): reg-staged fp32 x ----------------
__global__ __launch_bounds__(256) void stageA_kernel(
    const float* __restrict__ x, const unsigned short* __restrict__ Abf,
    const float* __restrict__ gate, unsigned short* __restrict__ z) {
  __shared__ unsigned short As[128 * 32];
  __shared__ unsigned short Bs[128 * 32];
  __shared__ float gl[128 * 16];
  const int tid = threadIdx.x;
  const int bid = blockIdx.x;
  const int mt = (bid & 7) + (bid >> 5) * 8;
  const int nt = (bid >> 3) & 3;
  const size_t m0 = (size_t)mt * 128;
  const int n0 = nt * 128;

  for (int i = 0; i < 8; i++) {
    int f = i * 256 + tid;
    gl[f] = gate[(m0 + (f >> 4)) * NE + (n0 >> 3) + (f & 15)];
  }
  const int wid = tid >> 6, lane = tid & 63;
  const int wm = (wid & 1) * 64, wn = (wid >> 1) * 64;
  const int lr = lane & 15, lq = lane >> 4;
  floatx4 acc[4][4];
  for (int i = 0; i < 4; i++)
    for (int j = 0; j < 4; j++) acc[i][j] = 0.0f;

  for (int k0 = 0; k0 < IN_F; k0 += 32) {
    __syncthreads();
    {
      int c4 = (tid & 7) * 4;
      int rbase = tid >> 3;
      for (int p = 0; p < 4; p++) {
        int row = p * 32 + rbase;
        float4 v = *(const float4*)(x + (m0 + row) * IN_F + k0 + c4);
        ushort4 h;
        h.x = f2bf_ru(v.x); h.y = f2bf_ru(v.y);
        h.z = f2bf_ru(v.z); h.w = f2bf_ru(v.w);
        *(ushort4*)(As + row * 32 + c4) = h;
      }
    }
    for (int p = 0; p < 2; p++) {
      int f = p * 256 + tid;
      int row = f >> 2, c8 = (f & 3) * 8;
      float4 v = *(const float4*)(Abf + (size_t)(n0 + row) * IN_F + k0 + c8);
      *(float4*)(Bs + row * 32 + c8) = v;
    }
    __syncthreads();
    short8 a[4], b[4];
    for (int i = 0; i < 4; i++) a[i] = *(const short8*)(As + (wm + i * 16 + lr) * 32 + lq * 8);
    for (int j = 0; j < 4; j++) b[j] = *(const short8*)(Bs + (wn + j * 16 + lr) * 32 + lq * 8);
    for (int i = 0; i < 4; i++)
      for (int j = 0; j < 4; j++)
        acc[i][j] = __builtin_amdgcn_mfma_f32_16x16x32_bf16(a[i], b[j], acc[i][j], 0, 0, 0);
  }
  for (int i = 0; i < 4; i++) {
    for (int j = 0; j < 4; j++) {
      int cl = wn + j * 16 + lr;
      int el = cl >> 3;
      for (int g = 0; g < 4; g++) {
        int rl = wm + i * 16 + lq * 4 + g;
        float v = acc[i][j][g] * gl[rl * 16 + el];
        z[(m0 + rl) * BOT + n0 + cl] = f2bf_ru(v);
      }
    }
  }
}

// ---------------- stage B (fast): out = z @ B^T * 2.0, global_load_lds staging ----------------
// 128x128 tile, BK=32, grid = 4096
__global__ __launch_bounds__(256) void stageB_fast(
    const unsigned short* __restrict__ z, const unsigned short* __restrict__ Bbf,
    float* __restrict__ out) {
  __shared__ unsigned short As[128 * 32];
  __shared__ unsigned short Bs[128 * 32];
  const int tid = threadIdx.x;
  const int bid = blockIdx.x;
  // XCD swizzle: each XCD owns 16 m-tiles x 32 n-tiles (B panel 4MB fits its L2)
  const int xc = bid & 7, ii = bid >> 3;
  const int mt = xc * 16 + (ii >> 5);
  const int nt = ii & 31;
  const size_t m0 = (size_t)mt * 128;
  const int n0 = nt * 128;
  const int wid = tid >> 6, lane = tid & 63;
  const int wm = (wid & 1) * 64, wn = (wid >> 1) * 64;
  const int lr = lane & 15, lq = lane >> 4;
  floatx4 acc[4][4];
  for (int i = 0; i < 4; i++)
    for (int j = 0; j < 4; j++) acc[i][j] = 0.0f;

  const int q0 = wid * 64 + lane;
  const int r0 = q0 >> 2, c0 = (q0 & 3) * 8;
  const int q1 = 256 + q0;
  const int r1 = q1 >> 2, c1 = (q1 & 3) * 8;
  const unsigned short* gA0 = z + (m0 + r0) * BOT + c0;
  const unsigned short* gA1 = z + (m0 + r1) * BOT + c1;
  const unsigned short* gB0 = Bbf + (size_t)(n0 + r0) * BOT + c0;
  const unsigned short* gB1 = Bbf + (size_t)(n0 + r1) * BOT + c1;
  unsigned short* lA0 = As + (wid * 64) * 8;
  unsigned short* lA1 = As + (256 + wid * 64) * 8;
  unsigned short* lB0 = Bs + (wid * 64) * 8;
  unsigned short* lB1 = Bs + (256 + wid * 64) * 8;

  for (int k0 = 0; k0 < BOT; k0 += 32) {
    gl2lds16(gA0 + k0, lA0);
    gl2lds16(gA1 + k0, lA1);
    gl2lds16(gB0 + k0, lB0);
    gl2lds16(gB1 + k0, lB1);
    __syncthreads();
    short8 a[4], b[4];
    for (int i = 0; i < 4; i++) a[i] = *(const short8*)(As + (wm + i * 16 + lr) * 32 + lq * 8);
    for (int j = 0; j < 4; j++) b[j] = *(const short8*)(Bs + (wn + j * 16 + lr) * 32 + lq * 8);
    for (int i = 0; i < 4; i++)
      for (int j = 0; j < 4; j++)
        acc[i][j] = __builtin_amdgcn_mfma_f32_16x16x32_bf16(a[i], b[j], acc[i][j], 0, 0, 0);
    __syncthreads();
  }
  for (int i = 0; i < 4; i++) {
    for (int j = 0; j < 4; j++) {
      int cl = wn + j * 16 + lr;
      for (int g = 0; g < 4; g++) {
        int rl = wm + i * 16 + lq * 4 + g;
        out[(m0 + rl) * OUT_F + n0 + cl] = acc[i][j][g] * 2.0f;  // SCALING = 32/16
      }
    }
  }
}

extern "C" void kernel_launch(void* const* d_in, const int* in_sizes, int n_in,
                              void* d_out, int out_size, void* d_ws, size_t ws_size,
                              hipStream_t stream) {
  const float* x    = (const float*)d_in[0];
  const float* A_w  = (const float*)d_in[1];
  const float* B_w  = (const float*)d_in[2];
  const float* Wq   = (const float*)d_in[3];
  const float* keys = (const float*)d_in[4];
  float* out = (float*)d_out;

  char* ws = (char*)d_ws;
  float* gate          = (float*)ws;                        // 16384*64*4   = 4  MB
  unsigned short* zbuf = (unsigned short*)(ws + (4 << 20)); // 16384*512*2  = 16 MB
  unsigned short* Abf  = (unsigned short*)(ws + (20 << 20)); // 4 MB
  unsigned short* Bbf  = (unsigned short*)(ws + (24 << 20)); // 4 MB
  unsigned short* xbf  = (unsigned short*)(ws + (28 << 20)); // 16384*4096*2 = 128 MB
  const int fast = ws_size >= ((size_t)156 << 20);

  hipLaunchKernelGGL(prep_kernel, dim3(8192), dim3(256), 0, stream, A_w, B_w, Abf, Bbf);
  hipLaunchKernelGGL(router_kernel, dim3(512), dim3(256), 0, stream, x, Wq, keys, gate,
                     xbf, fast);
  if (fast)
    hipLaunchKernelGGL(stageA_fast, dim3(512), dim3(256), 0, stream, xbf, Abf, gate, zbuf);
  else
    hipLaunchKernelGGL(stageA_kernel, dim3(512), dim3(256), 0, stream, x, Abf, gate, zbuf);
  hipLaunchKernelGGL(stageB_fast, dim3(4096), dim3(256), 0, stream, zbuf, Bbf, out);
}